// Round 3
// baseline (165.041 us; speedup 1.0000x reference)
//
#include <hip/hip_runtime.h>

#define N_NODES 100000
#define N_EDGES 800000
#define IN_FEATS 128
#define NUM_CLASSES 64

#define CAP    40       // per-node list slots: lambda=8, P(deg>40)~3e-16/node
#define NBKT   12500    // gather buckets: 8 dst nodes each

// Fused K1 grid: every 5th block is a scatter block -> concurrent with gemm.
#define K1_GRID 1955    // 391 groups of 5: 4 gemm-role + 1 scatter-role

typedef short bf16x8 __attribute__((ext_vector_type(8)));
typedef float f32x4  __attribute__((ext_vector_type(4)));

static __device__ __forceinline__ unsigned short f2bf(float f) {
    unsigned u = __float_as_uint(f);
    unsigned r = (u + 0x7fffu + ((u >> 16) & 1u)) >> 16;
    return (unsigned short)r;
}
static __device__ __forceinline__ float bf2f(unsigned short v) {
    return __uint_as_float(((unsigned)v) << 16);
}

// ---------------------------------------------------------------------------
// gemm role: y16 = bf16(x @ W^T) via MFMA 16x16x32 bf16. (R4-proven body)
// smem usage: Wf 16384 B + Xs 17408 B = 33792 B.
// ---------------------------------------------------------------------------
static __device__ __forceinline__ void gemm_body(char* smem, int gid,
                                                 const float* __restrict__ x,
                                                 const float* __restrict__ W,
                                                 unsigned short* __restrict__ y16) {
    const long base = (long)gid * 64;
    if (base >= N_NODES) return;   // uniform per block

    unsigned short* Wf = (unsigned short*)smem;                    // [4*4*64*8]
    typedef unsigned short XsRow[136];
    XsRow* Xs = (XsRow*)(smem + 16384);                            // [64][136]

    const int tid = threadIdx.x;

    for (int i = tid; i < 4 * 4 * 64 * 8; i += 256) {
        const int j    = i & 7;
        const int lane = (i >> 3) & 63;
        const int t    = (i >> 9) & 3;
        const int s    = i >> 11;
        const int k = s * 32 + ((lane >> 4) << 3) + j;
        const int c = t * 16 + (lane & 15);
        Wf[i] = f2bf(W[c * IN_FEATS + k]);
    }

#pragma unroll
    for (int it = 0; it < 8; ++it) {
        const int i   = tid + it * 256;
        const int row = i >> 5;
        const int c4  = (i & 31) << 2;
        const long node = base + row;
        float4 v = make_float4(0.f, 0.f, 0.f, 0.f);
        if (node < N_NODES) v = *(const float4*)&x[node * IN_FEATS + c4];
        ushort4 w4;
        w4.x = f2bf(v.x); w4.y = f2bf(v.y); w4.z = f2bf(v.z); w4.w = f2bf(v.w);
        *(ushort4*)&Xs[row][c4] = w4;
    }
    __syncthreads();

    const int wave = tid >> 6;
    const int lane = tid & 63;
    const long nb  = base + wave * 16;

    bf16x8 wf[4][4];
#pragma unroll
    for (int s = 0; s < 4; ++s)
#pragma unroll
        for (int t = 0; t < 4; ++t)
            wf[s][t] = *(const bf16x8*)&Wf[(((s * 4 + t) * 64) + lane) * 8];

    f32x4 acc[4];
#pragma unroll
    for (int t = 0; t < 4; ++t) acc[t] = (f32x4){0.f, 0.f, 0.f, 0.f};

    const int m  = lane & 15;
    const int kq = lane >> 4;
    const unsigned short* arow = &Xs[wave * 16 + m][kq * 8];

#pragma unroll
    for (int s = 0; s < 4; ++s) {
        bf16x8 af = *(const bf16x8*)(arow + s * 32);
#pragma unroll
        for (int t = 0; t < 4; ++t)
            acc[t] = __builtin_amdgcn_mfma_f32_16x16x32_bf16(af, wf[s][t], acc[t], 0, 0, 0);
    }

    const int ccol  = lane & 15;
    const int rbase = (lane >> 4) << 2;
#pragma unroll
    for (int t = 0; t < 4; ++t) {
#pragma unroll
        for (int r = 0; r < 4; ++r) {
            const long n2 = nb + rbase + r;
            if (n2 < N_NODES)
                y16[n2 * NUM_CLASSES + t * 16 + ccol] = f2bf(acc[t][r]);
        }
    }
}

// ---------------------------------------------------------------------------
// scatter role (v4): DIRECT per-node scatter. One device atomicAdd per edge
// (800k atomics over 100k addresses, lambda=8 -> ~4 us of TCC throughput)
// replaces the entire p1-binning + stage + scatter_p2 pipeline. cnt[d] ends
// as the EXACT in-degree (exact normalization denominator for free).
// 8 independent edges per thread -> atomics pipelined via vmcnt.
// ---------------------------------------------------------------------------
static __device__ __forceinline__ void scat_body(int sid,
                                                 const int* __restrict__ esrc,
                                                 const int* __restrict__ edst,
                                                 int* __restrict__ cnt,
                                                 unsigned* __restrict__ pairs) {
    const int e0 = sid * 2048 + threadIdx.x;
#pragma unroll
    for (int it = 0; it < 8; ++it) {
        const int e = e0 + it * 256;
        if (e < N_EDGES) {
            const int s = esrc[e];
            const int d = edst[e];
            const int r = atomicAdd(&cnt[d], 1);
            if (r < CAP) pairs[(size_t)d * CAP + r] = (unsigned)s;
        }
    }
}

// ---------------------------------------------------------------------------
// K1: fused gemm + direct scatter, roles interleaved (bid%5==4 -> scatter)
// so both kinds are co-resident: MFMA/LDS-bound gemm overlaps the
// latency-bound atomic scatter.
// ---------------------------------------------------------------------------
__global__ __launch_bounds__(256) void k1_gemm_scatter(const float* __restrict__ x,
                                                       const float* __restrict__ W,
                                                       unsigned short* __restrict__ y16,
                                                       const int* __restrict__ esrc,
                                                       const int* __restrict__ edst,
                                                       int* __restrict__ cnt,
                                                       unsigned* __restrict__ pairs) {
    __shared__ __align__(16) char smem[33792];
    const int bid = blockIdx.x;
    const int r   = bid % 5;
    if (r == 4) {
        scat_body(bid / 5, esrc, edst, cnt, pairs);
    } else {
        gemm_body(smem, (bid / 5) * 4 + r, x, W, y16);
    }
}

// ---------------------------------------------------------------------------
// Gather (v4): one WAVE per bucket of 8 nodes; lane = (node g = lane>>3,
// class-octet q = lane&7). Per-node lists are read with a register layout
// that keeps bpermute register indices LOOP-UNIFORM: lane (g,q) preloads its
// own node's slots {q, q+8, ..., q+32}, so edge j of node g lives in
// register r[j>>3] of lane (g<<3)|(j&7). One bpermute + one 16 B row-load
// per edge, 8 independent loads in flight per chunk, 8 concurrent per-node
// accumulator chains. Masked slots load row 0 (permanent L1 hit). ZERO LDS.
// ---------------------------------------------------------------------------
__global__ __launch_bounds__(256) void gather_node(const unsigned short* __restrict__ y16,
                                                   const unsigned* __restrict__ pairs,
                                                   const int* __restrict__ cnt,
                                                   const float* __restrict__ b,
                                                   float* __restrict__ out) {
    const int tid  = threadIdx.x;
    const int wave = tid >> 6;
    const int lane = tid & 63;
    const int bkt  = blockIdx.x * 4 + wave;      // < 12500 (grid is exact)
    const int g0   = bkt << 3;                   // first dst node of bucket

    const int g = lane >> 3;                     // node within bucket (0..7)
    const int q = lane & 7;                      // class octet (classes q*8..q*8+7)
    const size_t v = (size_t)(g0 + g);           // this lane-group's dst node

    // true in-degrees in lanes 0..7 -> broadcast to groups
    int cc = 0;
    if (lane < 8) cc = cnt[g0 + lane];
    const int myc_full = __shfl(cc, g);          // exact denominator
    const int myc      = min(myc_full, CAP);     // entries actually present

    // wave-uniform max list length (myc uniform within each 8-lane group)
    int mc = myc;
    mc = max(mc, __shfl_xor(mc, 8));
    mc = max(mc, __shfl_xor(mc, 16));
    mc = max(mc, __shfl_xor(mc, 32));
    const int maxc = __builtin_amdgcn_readfirstlane(mc);

    // preload this node's list: slot q+8t into r[t]  (garbage beyond myc is
    // masked later; addresses stay inside the pairs region: v<100000, q+32<40)
    const unsigned* pn = pairs + v * CAP;
    int r[5];
#pragma unroll
    for (int t = 0; t < 5; ++t) r[t] = (int)pn[q + 8 * t];

    f32x4 accA = {0.f, 0.f, 0.f, 0.f};
    f32x4 accB = {0.f, 0.f, 0.f, 0.f};

#pragma unroll
    for (int t = 0; t < 5; ++t) {
        if (t * 8 < maxc) {
            bf16x8 h[8];
            int    ok[8];
#pragma unroll
            for (int jj = 0; jj < 8; ++jj) {
                const int jt = t * 8 + jj;
                unsigned p = (unsigned)__shfl(r[t], (lane & 56) | jj) & 0x1FFFFu;
                ok[jj] = (jt < myc);
                p = ok[jj] ? p : 0u;             // masked lanes hit row 0 (L1)
                h[jj] = *(const bf16x8*)&y16[(size_t)p * NUM_CLASSES + q * 8];
            }
#pragma unroll
            for (int jj = 0; jj < 8; ++jj) {
                if (ok[jj]) {
#pragma unroll
                    for (int k = 0; k < 4; ++k) accA[k] += bf2f((unsigned short)h[jj][k]);
#pragma unroll
                    for (int k = 0; k < 4; ++k) accB[k] += bf2f((unsigned short)h[jj][4 + k]);
                }
            }
        }
    }

    // epilogue: self + exact normalize + bias; lane writes 8 consecutive floats
    const bf16x8 hs = *(const bf16x8*)&y16[v * NUM_CLASSES + q * 8];
    const float inv = 1.0f / (float)(myc_full + 1);
    const float4 b0 = *(const float4*)&b[q * 8];
    const float4 b1 = *(const float4*)&b[q * 8 + 4];

    float4 o0, o1;
    o0.x = (accA[0] + bf2f((unsigned short)hs[0])) * inv + b0.x;
    o0.y = (accA[1] + bf2f((unsigned short)hs[1])) * inv + b0.y;
    o0.z = (accA[2] + bf2f((unsigned short)hs[2])) * inv + b0.z;
    o0.w = (accA[3] + bf2f((unsigned short)hs[3])) * inv + b0.w;
    o1.x = (accB[0] + bf2f((unsigned short)hs[4])) * inv + b1.x;
    o1.y = (accB[1] + bf2f((unsigned short)hs[5])) * inv + b1.y;
    o1.z = (accB[2] + bf2f((unsigned short)hs[6])) * inv + b1.z;
    o1.w = (accB[3] + bf2f((unsigned short)hs[7])) * inv + b1.w;

    *(float4*)&out[v * NUM_CLASSES + q * 8]     = o0;
    *(float4*)&out[v * NUM_CLASSES + q * 8 + 4] = o1;
}

extern "C" void kernel_launch(void* const* d_in, const int* in_sizes, int n_in,
                              void* d_out, int out_size, void* d_ws, size_t ws_size,
                              hipStream_t stream) {
    const float* x    = (const float*)d_in[0];
    const int*   esrc = (const int*)d_in[1];
    const int*   edst = (const int*)d_in[2];
    const float* W    = (const float*)d_in[3];
    const float* b    = (const float*)d_in[4];
    float* out = (float*)d_out;

    // Workspace layout (~29.2 MB used; ws_size is 256 MiB per profile).
    char* p = (char*)d_ws;
    unsigned short* y16 = (unsigned short*)p;  p += (size_t)N_NODES * NUM_CLASSES * 2; // 12.8 MB
    unsigned* pairs     = (unsigned*)p;        p += (size_t)N_NODES * CAP * 4;         // 16.0 MB
    int* cnt            = (int*)p;             p += (size_t)N_NODES * 4;               // 400 KB

    // Zero the per-node degree counters (only buffer needing init).
    hipMemsetAsync(cnt, 0, (size_t)N_NODES * 4, stream);

    // Fused gemm + direct atomic scatter (concurrent roles).
    k1_gemm_scatter<<<K1_GRID, 256, 0, stream>>>(x, W, y16, esrc, edst, cnt, pairs);

    // Register-only gather + fused exact-normalize/bias. 3125 blocks.
    gather_node<<<NBKT / 4, 256, 0, stream>>>(y16, pairs, cnt, b, out);
}

// Round 4
// 157.498 us; speedup vs baseline: 1.0479x; 1.0479x over previous
//
#include <hip/hip_runtime.h>

#define N_NODES 100000
#define N_EDGES 800000
#define IN_FEATS 128
#define NUM_CLASSES 64

#define NSB    98       // super-buckets: dst >> 10 (1024 nodes each)
#define SCAP   9216     // staging slots per super-bucket (lambda=8192, +11 sigma)
#define BINCAP 56       // LDS bin slots per (block, sb): lambda=20.9 (+fallback path)
#define ECAP   2432     // LDS entry slots per quarter-sb (lambda=2048, +8.5 sigma)

// Fused K1 grid: every 5th block is a scatter_p1 block -> concurrent with gemm.
#define K1_GRID 1955    // 391 groups of 5: 4 gemm-role + 1 p1-role

typedef short bf16x8 __attribute__((ext_vector_type(8)));
typedef float f32x4  __attribute__((ext_vector_type(4)));

static __device__ __forceinline__ unsigned short f2bf(float f) {
    unsigned u = __float_as_uint(f);
    unsigned r = (u + 0x7fffu + ((u >> 16) & 1u)) >> 16;
    return (unsigned short)r;
}
static __device__ __forceinline__ float bf2f(unsigned short v) {
    return __uint_as_float(((unsigned)v) << 16);
}

// ---------------------------------------------------------------------------
// gemm role: y16 = bf16(x @ W^T) via MFMA 16x16x32 bf16. (R4-proven body)
// smem usage: Wf 16384 B + Xs 17408 B = 33792 B.
// ---------------------------------------------------------------------------
static __device__ __forceinline__ void gemm_body(char* smem, int gid,
                                                 const float* __restrict__ x,
                                                 const float* __restrict__ W,
                                                 unsigned short* __restrict__ y16) {
    const long base = (long)gid * 64;
    if (base >= N_NODES) return;   // uniform per block

    unsigned short* Wf = (unsigned short*)smem;                    // [4*4*64*8]
    typedef unsigned short XsRow[136];
    XsRow* Xs = (XsRow*)(smem + 16384);                            // [64][136]

    const int tid = threadIdx.x;

    for (int i = tid; i < 4 * 4 * 64 * 8; i += 256) {
        const int j    = i & 7;
        const int lane = (i >> 3) & 63;
        const int t    = (i >> 9) & 3;
        const int s    = i >> 11;
        const int k = s * 32 + ((lane >> 4) << 3) + j;
        const int c = t * 16 + (lane & 15);
        Wf[i] = f2bf(W[c * IN_FEATS + k]);
    }

#pragma unroll
    for (int it = 0; it < 8; ++it) {
        const int i   = tid + it * 256;
        const int row = i >> 5;
        const int c4  = (i & 31) << 2;
        const long node = base + row;
        float4 v = make_float4(0.f, 0.f, 0.f, 0.f);
        if (node < N_NODES) v = *(const float4*)&x[node * IN_FEATS + c4];
        ushort4 w4;
        w4.x = f2bf(v.x); w4.y = f2bf(v.y); w4.z = f2bf(v.z); w4.w = f2bf(v.w);
        *(ushort4*)&Xs[row][c4] = w4;
    }
    __syncthreads();

    const int wave = tid >> 6;
    const int lane = tid & 63;
    const long nb  = base + wave * 16;

    bf16x8 wf[4][4];
#pragma unroll
    for (int s = 0; s < 4; ++s)
#pragma unroll
        for (int t = 0; t < 4; ++t)
            wf[s][t] = *(const bf16x8*)&Wf[(((s * 4 + t) * 64) + lane) * 8];

    f32x4 acc[4];
#pragma unroll
    for (int t = 0; t < 4; ++t) acc[t] = (f32x4){0.f, 0.f, 0.f, 0.f};

    const int m  = lane & 15;
    const int kq = lane >> 4;
    const unsigned short* arow = &Xs[wave * 16 + m][kq * 8];

#pragma unroll
    for (int s = 0; s < 4; ++s) {
        bf16x8 af = *(const bf16x8*)(arow + s * 32);
#pragma unroll
        for (int t = 0; t < 4; ++t)
            acc[t] = __builtin_amdgcn_mfma_f32_16x16x32_bf16(af, wf[s][t], acc[t], 0, 0, 0);
    }

    const int ccol  = lane & 15;
    const int rbase = (lane >> 4) << 2;
#pragma unroll
    for (int t = 0; t < 4; ++t) {
#pragma unroll
        for (int r = 0; r < 4; ++r) {
            const long n2 = nb + rbase + r;
            if (n2 < N_NODES)
                y16[n2 * NUM_CLASSES + t * 16 + ccol] = f2bf(acc[t][r]);
        }
    }
}

// ---------------------------------------------------------------------------
// p1 role: LDS-bin 2048 edges by super-bucket, one global atomic per
// (block, sb) reserves contiguous staging slots -> all stage writes are
// (semi-)contiguous, no random-line RMW. (R7-proven body)
// smem usage: bins 21952 B + bcnt 392 B + bbase 392 B = 22736 B <= 33792.
// ---------------------------------------------------------------------------
static __device__ __forceinline__ void p1_body(char* smem, int p1id,
                                               const int* __restrict__ esrc,
                                               const int* __restrict__ edst,
                                               int* __restrict__ sbcur,
                                               unsigned* __restrict__ stage) {
    typedef unsigned BinRow[BINCAP];
    BinRow* bins = (BinRow*)smem;                       // [NSB][BINCAP]
    int* bcnt  = (int*)(smem + 21952);
    int* bbase = (int*)(smem + 21952 + 392);

    const int tid = threadIdx.x;
    for (int i = tid; i < NSB; i += 256) bcnt[i] = 0;
    __syncthreads();

    const int e0 = p1id * 2048;
#pragma unroll
    for (int it = 0; it < 8; ++it) {
        const int e = e0 + it * 256 + tid;
        if (e < N_EDGES) {
            const unsigned s  = (unsigned)esrc[e];
            const unsigned d  = (unsigned)edst[e];
            const unsigned sb = d >> 10;
            const unsigned pk = s | ((d & 1023u) << 17);
            const int p = atomicAdd(&bcnt[sb], 1);
            if (p < BINCAP) {
                bins[sb][p] = pk;
            } else {                       // rare LDS-bin overflow: direct global
                const int gp = atomicAdd(&sbcur[sb << 4], 1);
                if (gp < SCAP) stage[sb * SCAP + gp] = pk;
            }
        }
    }
    __syncthreads();

    if (tid < NSB) {
        const int c = min(bcnt[tid], BINCAP);
        bcnt[tid]  = c;
        bbase[tid] = atomicAdd(&sbcur[tid << 4], c);
    }
    __syncthreads();

    for (int i = tid; i < NSB * BINCAP; i += 256) {
        const int sb = i / BINCAP;
        const int k  = i - sb * BINCAP;
        if (k < bcnt[sb]) {
            const int pos = bbase[sb] + k;
            if (pos < SCAP) stage[sb * SCAP + pos] = bins[sb][k];
        }
    }
}

// ---------------------------------------------------------------------------
// K1: fused gemm + scatter_p1, roles interleaved (bid%5==4 -> p1) so both
// kinds are co-resident: MFMA/LDS-bound gemm overlaps latency-bound p1.
// ---------------------------------------------------------------------------
__global__ __launch_bounds__(256) void k1_gemm_scatter(const float* __restrict__ x,
                                                       const float* __restrict__ W,
                                                       unsigned short* __restrict__ y16,
                                                       const int* __restrict__ esrc,
                                                       const int* __restrict__ edst,
                                                       int* __restrict__ sbcur,
                                                       unsigned* __restrict__ stage) {
    __shared__ __align__(16) char smem[33792];
    const int bid = blockIdx.x;
    const int r   = bid % 5;
    if (r == 4) {
        p1_body(smem, bid / 5, esrc, edst, sbcur, stage);
    } else {
        gemm_body(smem, (bid / 5) * 4 + r, x, W, y16);
    }
}

// ---------------------------------------------------------------------------
// K2 (NEW, fuses scatter_p2 + gather): block = (sb, quarter q) owning 256
// dst nodes. Builds a per-node CSR ENTIRELY IN LDS (count -> wave-0 shfl
// prefix scan -> place), then gathers straight from LDS: 8-lane group per
// node (g=lane>>3), class-octet q8=lane&7, 4 independent 16 B y16 row loads
// in flight, 8 concurrent per-node acc chains per wave. No pairs/cnt_g
// global buffers, no extra launch. LDS 12.9 KB -> all 392 blocks resident.
// Denominator = exact pass-1 count.
// ---------------------------------------------------------------------------
__global__ __launch_bounds__(256) void bin_gather(const unsigned* __restrict__ stage,
                                                  const int* __restrict__ sbcur,
                                                  const unsigned short* __restrict__ y16,
                                                  const float* __restrict__ b,
                                                  float* __restrict__ out) {
    __shared__ int lcnt[256];
    __shared__ int loff[256];
    __shared__ int lcur[256];
    __shared__ unsigned entries[ECAP + 8];   // +8 pad: clamp-free masked reads

    const int sb   = blockIdx.x >> 2;
    const int q    = blockIdx.x & 3;
    const int tid  = threadIdx.x;
    const int wave = tid >> 6;
    const int lane = tid & 63;

    lcnt[tid] = 0;
    __syncthreads();

    const int ecnt = min(sbcur[sb << 4], SCAP);
    const unsigned* sp = stage + (size_t)sb * SCAP;

    // pass 1: count edges landing in this block's 256 nodes
    for (int i = tid; i < ecnt; i += 256) {
        const unsigned dlow = sp[i] >> 17;
        if ((int)(dlow >> 8) == q)
            atomicAdd(&lcnt[dlow & 255u], 1);
    }
    __syncthreads();

    // exclusive prefix scan of 256 counts (wave 0: 4 counts/lane + shfl scan)
    if (tid < 64) {
        const int i0 = tid << 2;
        const int c0 = lcnt[i0], c1 = lcnt[i0 + 1], c2 = lcnt[i0 + 2], c3 = lcnt[i0 + 3];
        const int sum = c0 + c1 + c2 + c3;
        int incl = sum;
#pragma unroll
        for (int s = 1; s < 64; s <<= 1) {
            const int v = __shfl_up(incl, s);
            if (tid >= s) incl += v;
        }
        int run = incl - sum;
        loff[i0]     = min(run, ECAP); lcur[i0]     = min(run, ECAP); run += c0;
        loff[i0 + 1] = min(run, ECAP); lcur[i0 + 1] = min(run, ECAP); run += c1;
        loff[i0 + 2] = min(run, ECAP); lcur[i0 + 2] = min(run, ECAP); run += c2;
        loff[i0 + 3] = min(run, ECAP); lcur[i0 + 3] = min(run, ECAP);
    }
    __syncthreads();

    // pass 2: place src indices, grouped by node
    for (int i = tid; i < ecnt; i += 256) {
        const unsigned pk   = sp[i];
        const unsigned dlow = pk >> 17;
        if ((int)(dlow >> 8) == q) {
            const int pos = atomicAdd(&lcur[dlow & 255u], 1);
            if (pos < ECAP) entries[pos] = pk & 0x1FFFFu;
        }
    }
    __syncthreads();

    // gather: 8 passes x (4 waves x 8 nodes); lane = (node g, class-octet q8)
    const int g     = lane >> 3;
    const int q8    = lane & 7;
    const int gbase = (sb << 10) + (q << 8);

    for (int p = 0; p < 8; ++p) {
        const int ln   = (p << 5) + (wave << 3) + g;
        const int deg  = lcnt[ln];                    // exact in-degree
        const int st   = loff[ln];
        const int degr = min(deg, ECAP - st);         // entries present

        int mc = degr;
        mc = max(mc, __shfl_xor(mc, 8));
        mc = max(mc, __shfl_xor(mc, 16));
        mc = max(mc, __shfl_xor(mc, 32));
        const int maxd = __builtin_amdgcn_readfirstlane(mc);

        f32x4 accA = {0.f, 0.f, 0.f, 0.f};
        f32x4 accB = {0.f, 0.f, 0.f, 0.f};

        for (int j = 0; j < maxd; j += 4) {
            bf16x8 h[4];
            int    ok[4];
#pragma unroll
            for (int t = 0; t < 4; ++t) {
                const int jt  = j + t;
                ok[t] = (jt < degr);
                const int idx = st + (ok[t] ? jt : 0);        // <= ECAP (padded)
                const unsigned src = entries[idx];            // LDS broadcast in group
                h[t] = *(const bf16x8*)&y16[(size_t)src * NUM_CLASSES + q8 * 8];
            }
#pragma unroll
            for (int t = 0; t < 4; ++t) {
                if (ok[t]) {
#pragma unroll
                    for (int k = 0; k < 4; ++k) accA[k] += bf2f((unsigned short)h[t][k]);
#pragma unroll
                    for (int k = 0; k < 4; ++k) accB[k] += bf2f((unsigned short)h[t][4 + k]);
                }
            }
        }

        const int gn = gbase + ln;
        if (gn < N_NODES) {
            const bf16x8 hs = *(const bf16x8*)&y16[(size_t)gn * NUM_CLASSES + q8 * 8];
            const float inv = 1.0f / (float)(deg + 1);
            const float4 b0 = *(const float4*)&b[q8 * 8];
            const float4 b1 = *(const float4*)&b[q8 * 8 + 4];

            float4 o0, o1;
            o0.x = (accA[0] + bf2f((unsigned short)hs[0])) * inv + b0.x;
            o0.y = (accA[1] + bf2f((unsigned short)hs[1])) * inv + b0.y;
            o0.z = (accA[2] + bf2f((unsigned short)hs[2])) * inv + b0.z;
            o0.w = (accA[3] + bf2f((unsigned short)hs[3])) * inv + b0.w;
            o1.x = (accB[0] + bf2f((unsigned short)hs[4])) * inv + b1.x;
            o1.y = (accB[1] + bf2f((unsigned short)hs[5])) * inv + b1.y;
            o1.z = (accB[2] + bf2f((unsigned short)hs[6])) * inv + b1.z;
            o1.w = (accB[3] + bf2f((unsigned short)hs[7])) * inv + b1.w;

            *(float4*)&out[(size_t)gn * NUM_CLASSES + q8 * 8]     = o0;
            *(float4*)&out[(size_t)gn * NUM_CLASSES + q8 * 8 + 4] = o1;
        }
    }
}

extern "C" void kernel_launch(void* const* d_in, const int* in_sizes, int n_in,
                              void* d_out, int out_size, void* d_ws, size_t ws_size,
                              hipStream_t stream) {
    const float* x    = (const float*)d_in[0];
    const int*   esrc = (const int*)d_in[1];
    const int*   edst = (const int*)d_in[2];
    const float* W    = (const float*)d_in[3];
    const float* b    = (const float*)d_in[4];
    float* out = (float*)d_out;

    // Workspace layout (~16.4 MB used; ws_size is 256 MiB per profile).
    char* p = (char*)d_ws;
    unsigned short* y16 = (unsigned short*)p;  p += (size_t)N_NODES * NUM_CLASSES * 2; // 12.8 MB
    unsigned* stage     = (unsigned*)p;        p += (size_t)NSB * SCAP * 4;            // 3.6 MB
    int* sbcur          = (int*)p;             p += (size_t)NSB * 16 * 4;              // 6.3 KB

    // Zero only the 98 line-padded super-bucket cursors (needed before p1 role).
    hipMemsetAsync(sbcur, 0, (size_t)NSB * 16 * 4, stream);

    // Fused gemm + scatter_p1 (concurrent roles).
    k1_gemm_scatter<<<K1_GRID, 256, 0, stream>>>(x, W, y16, esrc, edst, sbcur, stage);

    // Fused LDS-CSR bin + gather + normalize/bias. 392 blocks, all resident.
    bin_gather<<<NSB * 4, 256, 0, stream>>>(stage, sbcur, y16, b, out);
}

// Round 5
// 144.065 us; speedup vs baseline: 1.1456x; 1.0932x over previous
//
#include <hip/hip_runtime.h>

#define N_NODES 100000
#define N_EDGES 800000
#define IN_FEATS 128
#define NUM_CLASSES 64

#define NSB    98       // super-buckets: dst >> 10 (1024 nodes each)
#define SCAP   9216     // staging slots per super-bucket (lambda=8192, +11 sigma)
#define BINCAP 56       // LDS bin slots per (block, sb): lambda=20.9 (+fallback path)
#define ECAP   2432     // LDS entry slots per quarter-sb (lambda=2048, +8.5 sigma)

// Fused K1 grid: every 5th block is a scatter_p1 block -> concurrent with gemm.
#define K1_GRID 1955    // 391 groups of 5: 4 gemm-role + 1 p1-role

typedef short bf16x8 __attribute__((ext_vector_type(8)));
typedef float f32x4  __attribute__((ext_vector_type(4)));

static __device__ __forceinline__ unsigned short f2bf(float f) {
    unsigned u = __float_as_uint(f);
    unsigned r = (u + 0x7fffu + ((u >> 16) & 1u)) >> 16;
    return (unsigned short)r;
}
static __device__ __forceinline__ float bf2f(unsigned short v) {
    return __uint_as_float(((unsigned)v) << 16);
}

// ---------------------------------------------------------------------------
// gemm role: y16 = bf16(x @ W^T) via MFMA 16x16x32 bf16.
// C-write v2: pack the 16x64 wave tile into the wave-private Xs rows as
// bf16 (16 ds_write_b16/lane), then store 2 KB contiguous per wave as
// 2x dwordx4 per lane (vs 16 scattered 2 B stores/lane before).
// smem usage: Wf 16384 B + Xs 17408 B = 33792 B.
// ---------------------------------------------------------------------------
static __device__ __forceinline__ void gemm_body(char* smem, int gid,
                                                 const float* __restrict__ x,
                                                 const float* __restrict__ W,
                                                 unsigned short* __restrict__ y16) {
    const long base = (long)gid * 64;
    if (base >= N_NODES) return;   // uniform per block

    unsigned short* Wf = (unsigned short*)smem;                    // [4*4*64*8]
    typedef unsigned short XsRow[136];
    XsRow* Xs = (XsRow*)(smem + 16384);                            // [64][136]

    const int tid = threadIdx.x;

    for (int i = tid; i < 4 * 4 * 64 * 8; i += 256) {
        const int j    = i & 7;
        const int lane = (i >> 3) & 63;
        const int t    = (i >> 9) & 3;
        const int s    = i >> 11;
        const int k = s * 32 + ((lane >> 4) << 3) + j;
        const int c = t * 16 + (lane & 15);
        Wf[i] = f2bf(W[c * IN_FEATS + k]);
    }

#pragma unroll
    for (int it = 0; it < 8; ++it) {
        const int i   = tid + it * 256;
        const int row = i >> 5;
        const int c4  = (i & 31) << 2;
        const long node = base + row;
        float4 v = make_float4(0.f, 0.f, 0.f, 0.f);
        if (node < N_NODES) v = *(const float4*)&x[node * IN_FEATS + c4];
        ushort4 w4;
        w4.x = f2bf(v.x); w4.y = f2bf(v.y); w4.z = f2bf(v.z); w4.w = f2bf(v.w);
        *(ushort4*)&Xs[row][c4] = w4;
    }
    __syncthreads();

    const int wave = tid >> 6;
    const int lane = tid & 63;
    const long nb  = base + wave * 16;

    bf16x8 wf[4][4];
#pragma unroll
    for (int s = 0; s < 4; ++s)
#pragma unroll
        for (int t = 0; t < 4; ++t)
            wf[s][t] = *(const bf16x8*)&Wf[(((s * 4 + t) * 64) + lane) * 8];

    f32x4 acc[4];
#pragma unroll
    for (int t = 0; t < 4; ++t) acc[t] = (f32x4){0.f, 0.f, 0.f, 0.f};

    const int m  = lane & 15;
    const int kq = lane >> 4;
    const unsigned short* arow = &Xs[wave * 16 + m][kq * 8];

#pragma unroll
    for (int s = 0; s < 4; ++s) {
        bf16x8 af = *(const bf16x8*)(arow + s * 32);
#pragma unroll
        for (int t = 0; t < 4; ++t)
            acc[t] = __builtin_amdgcn_mfma_f32_16x16x32_bf16(af, wf[s][t], acc[t], 0, 0, 0);
    }

    // ---- C-write v2: LDS repack (wave-private rows) + coalesced 16 B stores
    const int ccol  = lane & 15;
    const int rbase = (lane >> 4) << 2;
#pragma unroll
    for (int t = 0; t < 4; ++t)
#pragma unroll
        for (int r = 0; r < 4; ++r)
            Xs[wave * 16 + rbase + r][t * 16 + ccol] = f2bf(acc[t][r]);

    const int orow = lane >> 2;          // 0..15 within wave tile
    const int ocb  = (lane & 3) << 4;    // col block of 16 classes
    const long n2  = nb + orow;
    if (n2 < N_NODES) {
        const bf16x8 o0 = *(const bf16x8*)&Xs[wave * 16 + orow][ocb];
        const bf16x8 o1 = *(const bf16x8*)&Xs[wave * 16 + orow][ocb + 8];
        *(bf16x8*)&y16[n2 * NUM_CLASSES + ocb]     = o0;
        *(bf16x8*)&y16[n2 * NUM_CLASSES + ocb + 8] = o1;
    }
}

// ---------------------------------------------------------------------------
// p1 role: LDS-bin 2048 edges by super-bucket, one global atomic per
// (block, sb) reserves contiguous staging slots -> all stage writes are
// (semi-)contiguous, no random-line RMW. (R7-proven body)
// smem usage: bins 21952 B + bcnt 392 B + bbase 392 B = 22736 B <= 33792.
// ---------------------------------------------------------------------------
static __device__ __forceinline__ void p1_body(char* smem, int p1id,
                                               const int* __restrict__ esrc,
                                               const int* __restrict__ edst,
                                               int* __restrict__ sbcur,
                                               unsigned* __restrict__ stage) {
    typedef unsigned BinRow[BINCAP];
    BinRow* bins = (BinRow*)smem;                       // [NSB][BINCAP]
    int* bcnt  = (int*)(smem + 21952);
    int* bbase = (int*)(smem + 21952 + 392);

    const int tid = threadIdx.x;
    for (int i = tid; i < NSB; i += 256) bcnt[i] = 0;
    __syncthreads();

    const int e0 = p1id * 2048;
#pragma unroll
    for (int it = 0; it < 8; ++it) {
        const int e = e0 + it * 256 + tid;
        if (e < N_EDGES) {
            const unsigned s  = (unsigned)esrc[e];
            const unsigned d  = (unsigned)edst[e];
            const unsigned sb = d >> 10;
            const unsigned pk = s | ((d & 1023u) << 17);
            const int p = atomicAdd(&bcnt[sb], 1);
            if (p < BINCAP) {
                bins[sb][p] = pk;
            } else {                       // rare LDS-bin overflow: direct global
                const int gp = atomicAdd(&sbcur[sb << 4], 1);
                if (gp < SCAP) stage[sb * SCAP + gp] = pk;
            }
        }
    }
    __syncthreads();

    if (tid < NSB) {
        const int c = min(bcnt[tid], BINCAP);
        bcnt[tid]  = c;
        bbase[tid] = atomicAdd(&sbcur[tid << 4], c);
    }
    __syncthreads();

    for (int i = tid; i < NSB * BINCAP; i += 256) {
        const int sb = i / BINCAP;
        const int k  = i - sb * BINCAP;
        if (k < bcnt[sb]) {
            const int pos = bbase[sb] + k;
            if (pos < SCAP) stage[sb * SCAP + pos] = bins[sb][k];
        }
    }
}

// ---------------------------------------------------------------------------
// K1: fused gemm + scatter_p1, roles interleaved (bid%5==4 -> p1) so both
// kinds are co-resident: MFMA/LDS-bound gemm overlaps latency-bound p1.
// ---------------------------------------------------------------------------
__global__ __launch_bounds__(256) void k1_gemm_scatter(const float* __restrict__ x,
                                                       const float* __restrict__ W,
                                                       unsigned short* __restrict__ y16,
                                                       const int* __restrict__ esrc,
                                                       const int* __restrict__ edst,
                                                       int* __restrict__ sbcur,
                                                       unsigned* __restrict__ stage) {
    __shared__ __align__(16) char smem[33792];
    const int bid = blockIdx.x;
    const int r   = bid % 5;
    if (r == 4) {
        p1_body(smem, bid / 5, esrc, edst, sbcur, stage);
    } else {
        gemm_body(smem, (bid / 5) * 4 + r, x, W, y16);
    }
}

// ---------------------------------------------------------------------------
// K2 (v2): block = (sb, quarter q) owning 256 dst nodes, now 512 THREADS
// (8 waves -> ~2x wave occupancy) and edge loop unrolled x8 (8 independent
// 16 B y16 row-loads in flight per wave). LDS CSR build unchanged:
// count -> wave-0 shfl prefix scan -> place. Gather: 8-lane group per node,
// class-octet q8 = lane&7, 8 concurrent per-node acc chains per wave.
// LDS 13.3 KB. Denominator = exact pass-1 count.
// ---------------------------------------------------------------------------
__global__ __launch_bounds__(512) void bin_gather(const unsigned* __restrict__ stage,
                                                  const int* __restrict__ sbcur,
                                                  const unsigned short* __restrict__ y16,
                                                  const float* __restrict__ b,
                                                  float* __restrict__ out) {
    __shared__ int lcnt[256];
    __shared__ int loff[256];
    __shared__ int lcur[256];
    __shared__ unsigned entries[ECAP + 8];   // +8 pad: clamp-free masked reads

    const int sb   = blockIdx.x >> 2;
    const int q    = blockIdx.x & 3;
    const int tid  = threadIdx.x;
    const int wave = tid >> 6;
    const int lane = tid & 63;

    if (tid < 256) lcnt[tid] = 0;
    __syncthreads();

    const int ecnt = min(sbcur[sb << 4], SCAP);
    const unsigned* sp = stage + (size_t)sb * SCAP;

    // pass 1: count edges landing in this block's 256 nodes
    for (int i = tid; i < ecnt; i += 512) {
        const unsigned dlow = sp[i] >> 17;
        if ((int)(dlow >> 8) == q)
            atomicAdd(&lcnt[dlow & 255u], 1);
    }
    __syncthreads();

    // exclusive prefix scan of 256 counts (wave 0: 4 counts/lane + shfl scan)
    if (tid < 64) {
        const int i0 = tid << 2;
        const int c0 = lcnt[i0], c1 = lcnt[i0 + 1], c2 = lcnt[i0 + 2], c3 = lcnt[i0 + 3];
        const int sum = c0 + c1 + c2 + c3;
        int incl = sum;
#pragma unroll
        for (int s = 1; s < 64; s <<= 1) {
            const int v = __shfl_up(incl, s);
            if (tid >= s) incl += v;
        }
        int run = incl - sum;
        loff[i0]     = min(run, ECAP); lcur[i0]     = min(run, ECAP); run += c0;
        loff[i0 + 1] = min(run, ECAP); lcur[i0 + 1] = min(run, ECAP); run += c1;
        loff[i0 + 2] = min(run, ECAP); lcur[i0 + 2] = min(run, ECAP); run += c2;
        loff[i0 + 3] = min(run, ECAP); lcur[i0 + 3] = min(run, ECAP);
    }
    __syncthreads();

    // pass 2: place src indices, grouped by node
    for (int i = tid; i < ecnt; i += 512) {
        const unsigned pk   = sp[i];
        const unsigned dlow = pk >> 17;
        if ((int)(dlow >> 8) == q) {
            const int pos = atomicAdd(&lcur[dlow & 255u], 1);
            if (pos < ECAP) entries[pos] = pk & 0x1FFFFu;
        }
    }
    __syncthreads();

    // gather: 4 passes x (8 waves x 8 nodes); lane = (node g, class-octet q8)
    const int g     = lane >> 3;
    const int q8    = lane & 7;
    const int gbase = (sb << 10) + (q << 8);

    for (int p = 0; p < 4; ++p) {
        const int ln   = (p << 6) + (wave << 3) + g;
        const int deg  = lcnt[ln];                    // exact in-degree
        const int st   = loff[ln];
        const int degr = min(deg, ECAP - st);         // entries present

        int mc = degr;
        mc = max(mc, __shfl_xor(mc, 8));
        mc = max(mc, __shfl_xor(mc, 16));
        mc = max(mc, __shfl_xor(mc, 32));
        const int maxd = __builtin_amdgcn_readfirstlane(mc);

        f32x4 accA = {0.f, 0.f, 0.f, 0.f};
        f32x4 accB = {0.f, 0.f, 0.f, 0.f};

        for (int j = 0; j < maxd; j += 8) {
            bf16x8 h[8];
            int    ok[8];
#pragma unroll
            for (int t = 0; t < 8; ++t) {
                const int jt  = j + t;
                ok[t] = (jt < degr);
                const int idx = st + (ok[t] ? jt : 0);        // <= ECAP (padded)
                const unsigned src = entries[idx];            // LDS broadcast in group
                h[t] = *(const bf16x8*)&y16[(size_t)src * NUM_CLASSES + q8 * 8];
            }
#pragma unroll
            for (int t = 0; t < 8; ++t) {
                if (ok[t]) {
#pragma unroll
                    for (int k = 0; k < 4; ++k) accA[k] += bf2f((unsigned short)h[t][k]);
#pragma unroll
                    for (int k = 0; k < 4; ++k) accB[k] += bf2f((unsigned short)h[t][4 + k]);
                }
            }
        }

        const int gn = gbase + ln;
        if (gn < N_NODES) {
            const bf16x8 hs = *(const bf16x8*)&y16[(size_t)gn * NUM_CLASSES + q8 * 8];
            const float inv = 1.0f / (float)(deg + 1);
            const float4 b0 = *(const float4*)&b[q8 * 8];
            const float4 b1 = *(const float4*)&b[q8 * 8 + 4];

            float4 o0, o1;
            o0.x = (accA[0] + bf2f((unsigned short)hs[0])) * inv + b0.x;
            o0.y = (accA[1] + bf2f((unsigned short)hs[1])) * inv + b0.y;
            o0.z = (accA[2] + bf2f((unsigned short)hs[2])) * inv + b0.z;
            o0.w = (accA[3] + bf2f((unsigned short)hs[3])) * inv + b0.w;
            o1.x = (accB[0] + bf2f((unsigned short)hs[4])) * inv + b1.x;
            o1.y = (accB[1] + bf2f((unsigned short)hs[5])) * inv + b1.y;
            o1.z = (accB[2] + bf2f((unsigned short)hs[6])) * inv + b1.z;
            o1.w = (accB[3] + bf2f((unsigned short)hs[7])) * inv + b1.w;

            *(float4*)&out[(size_t)gn * NUM_CLASSES + q8 * 8]     = o0;
            *(float4*)&out[(size_t)gn * NUM_CLASSES + q8 * 8 + 4] = o1;
        }
    }
}

extern "C" void kernel_launch(void* const* d_in, const int* in_sizes, int n_in,
                              void* d_out, int out_size, void* d_ws, size_t ws_size,
                              hipStream_t stream) {
    const float* x    = (const float*)d_in[0];
    const int*   esrc = (const int*)d_in[1];
    const int*   edst = (const int*)d_in[2];
    const float* W    = (const float*)d_in[3];
    const float* b    = (const float*)d_in[4];
    float* out = (float*)d_out;

    // Workspace layout (~16.4 MB used; ws_size is 256 MiB per profile).
    char* p = (char*)d_ws;
    unsigned short* y16 = (unsigned short*)p;  p += (size_t)N_NODES * NUM_CLASSES * 2; // 12.8 MB
    unsigned* stage     = (unsigned*)p;        p += (size_t)NSB * SCAP * 4;            // 3.6 MB
    int* sbcur          = (int*)p;             p += (size_t)NSB * 16 * 4;              // 6.3 KB

    // Zero only the 98 line-padded super-bucket cursors (needed before p1 role).
    hipMemsetAsync(sbcur, 0, (size_t)NSB * 16 * 4, stream);

    // Fused gemm + scatter_p1 (concurrent roles).
    k1_gemm_scatter<<<K1_GRID, 256, 0, stream>>>(x, W, y16, esrc, edst, sbcur, stage);

    // Fused LDS-CSR bin + gather + normalize/bias. 392 blocks x 8 waves.
    bin_gather<<<NSB * 4, 512, 0, stream>>>(stage, sbcur, y16, b, out);
}